// Round 2
// baseline (3188.721 us; speedup 1.0000x reference)
//
#include <hip/hip_runtime.h>
#include <hip/hip_bf16.h>

#define HH 512
#define WW 512
#define HWSZ (512 * 512)
#define CIN 64
#define MID 32

#define TS 16
#define HC 18            // TS + 2 halo
#define NCOL (HC * HC)   // 324 staging columns
// Per-column LDS layout (uint2 units): [0..7]=x1 (32ch bf16), [8..23]=x3 (64ch bf16), [24]=pad
// stride 25 uint2 = 50 words -> bank step 18 mod 32 (16 distinct banks per row) -> conflict-free
#define CSTR 25

__device__ __forceinline__ unsigned pack_bf2(float a, float b) {
    __hip_bfloat162 h = __float22bfloat162_rn(float2{a, b});
    unsigned u;
    __builtin_memcpy(&u, &h, 4);
    return u;  // low16 = a, high16 = b
}
__device__ __forceinline__ float bflo(unsigned u) { return __uint_as_float(u << 16); }
__device__ __forceinline__ float bfhi(unsigned u) { return __uint_as_float(u & 0xffff0000u); }
// sigmoid(z) with t = -log2(e)*z precomputed: 1/(1+2^t)
__device__ __forceinline__ float sigm_t(float t) {
    return __builtin_amdgcn_rcpf(1.f + __builtin_amdgcn_exp2f(t));
}

__global__ __launch_bounds__(256, 2)
void fused_local_attn(const float* __restrict__ x,
                      const float* __restrict__ w1, const float* __restrict__ b1,
                      const float* __restrict__ w2, const float* __restrict__ b2,
                      const float* __restrict__ w3, const float* __restrict__ b3,
                      const float* __restrict__ gamma,
                      float* __restrict__ out)
{
    __shared__ uint2 sT[NCOL * CSTR];  // 324*25*8 = 64800 B

    const int tid = threadIdx.x;
    const int lx = tid & 15, ly = tid >> 4;
    const int b  = blockIdx.z;
    const int w0 = blockIdx.x * TS, h0 = blockIdx.y * TS;
    const int hh = h0 + ly, ww = w0 + lx;

    const float* xb = x + (size_t)b * CIN * HWSZ;
    const float* xp = xb + hh * WW + ww;   // own pixel, channel-strided

    // ================= Phase 1: own pixel -> x1, x2 (regs), x3 =================
    const int colo = (ly + 1) * HC + (lx + 1);
    float x2n[MID];
    {
        float a1[MID], a2[MID];
#pragma unroll
        for (int oc = 0; oc < MID; ++oc) { a1[oc] = b1[oc]; a2[oc] = b2[oc]; }
#pragma unroll 4
        for (int ic = 0; ic < CIN; ++ic) {
            float xv = xp[(size_t)ic * HWSZ];
#pragma unroll
            for (int oc = 0; oc < MID; ++oc) {
                a1[oc] += w1[oc * CIN + ic] * xv;
                a2[oc] += w2[oc * CIN + ic] * xv;
            }
        }
        uint2* p1 = &sT[colo * CSTR];
#pragma unroll
        for (int p = 0; p < 8; ++p)
            p1[p] = uint2{pack_bf2(a1[4 * p], a1[4 * p + 1]),
                          pack_bf2(a1[4 * p + 2], a1[4 * p + 3])};
#pragma unroll
        for (int oc = 0; oc < MID; ++oc) x2n[oc] = a2[oc] * -1.4426950408889634f;
    }
    {
        float a3[CIN];
#pragma unroll
        for (int c = 0; c < CIN; ++c) a3[c] = b3[c];
#pragma unroll 4
        for (int ic = 0; ic < CIN; ++ic) {
            float xv = xp[(size_t)ic * HWSZ];  // L1 hit
#pragma unroll
            for (int c = 0; c < CIN; ++c) a3[c] += w3[c * CIN + ic] * xv;
        }
        uint2* p3 = &sT[colo * CSTR + 8];
#pragma unroll
        for (int p = 0; p < 16; ++p)
            p3[p] = uint2{pack_bf2(a3[4 * p], a3[4 * p + 1]),
                          pack_bf2(a3[4 * p + 2], a3[4 * p + 3])};
    }

    // ================= Phase 2: 68 halo columns (threads 0..67) =================
    if (tid < 68) {
        int sy, sx;
        if (tid < 18)      { sy = 0;        sx = tid; }
        else if (tid < 36) { sy = 17;       sx = tid - 18; }
        else if (tid < 52) { sy = tid - 35; sx = 0; }
        else               { sy = tid - 51; sx = 17; }
        const int col = sy * HC + sx;
        const int gh = h0 - 1 + sy, gw = w0 - 1 + sx;
        const bool valid = (gh >= 0) && (gh < HH) && (gw >= 0) && (gw < WW);
        float a1[MID], a3[CIN];
#pragma unroll
        for (int oc = 0; oc < MID; ++oc) a1[oc] = valid ? b1[oc] : 0.f;
#pragma unroll
        for (int c = 0; c < CIN; ++c) a3[c] = valid ? b3[c] : 0.f;
        if (valid) {
            const float* xq = xb + gh * WW + gw;
#pragma unroll 4
            for (int ic = 0; ic < CIN; ++ic) {
                float xv = xq[(size_t)ic * HWSZ];
#pragma unroll
                for (int oc = 0; oc < MID; ++oc) a1[oc] += w1[oc * CIN + ic] * xv;
#pragma unroll
                for (int c = 0; c < CIN; ++c) a3[c] += w3[c * CIN + ic] * xv;
            }
        }
        uint2* p1 = &sT[col * CSTR];
#pragma unroll
        for (int p = 0; p < 8; ++p)
            p1[p] = uint2{pack_bf2(a1[4 * p], a1[4 * p + 1]),
                          pack_bf2(a1[4 * p + 2], a1[4 * p + 3])};
        uint2* p3 = &sT[col * CSTR + 8];
#pragma unroll
        for (int p = 0; p < 16; ++p)
            p3[p] = uint2{pack_bf2(a3[4 * p], a3[4 * p + 1]),
                          pack_bf2(a3[4 * p + 2], a3[4 * p + 3])};
    }
    __syncthreads();

    // ================= S[9]: branch-free (OOB columns have x3=0) =================
    float S[9];
#pragma unroll
    for (int j = 0; j < 9; ++j) {
        const int dy = j / 3, dx = j % 3;
        const int col = (ly + dy) * HC + (lx + dx);
        const uint2* q = &sT[col * CSTR];
        float s = 0.f;
#pragma unroll
        for (int p = 0; p < 8; ++p) {
            uint2 u = q[p];
            s += sigm_t(x2n[4 * p]     * bflo(u.x));
            s += sigm_t(x2n[4 * p + 1] * bfhi(u.x));
            s += sigm_t(x2n[4 * p + 2] * bflo(u.y));
            s += sigm_t(x2n[4 * p + 3] * bfhi(u.y));
        }
        S[j] = s;
    }

    // ================= Gather: acc[c] = sum_j S_j * x3[c, q_j] =================
    float acc[CIN];
#pragma unroll
    for (int c = 0; c < CIN; ++c) acc[c] = 0.f;
#pragma unroll
    for (int j = 0; j < 9; ++j) {
        const int dy = j / 3, dx = j % 3;
        const int col = (ly + dy) * HC + (lx + dx);
        const float Sj = S[j];
        const uint2* q = &sT[col * CSTR + 8];
#pragma unroll
        for (int t = 0; t < 16; ++t) {
            uint2 u = q[t];
            acc[4 * t]     += Sj * bflo(u.x);
            acc[4 * t + 1] += Sj * bfhi(u.x);
            acc[4 * t + 2] += Sj * bflo(u.y);
            acc[4 * t + 3] += Sj * bfhi(u.y);
        }
    }

    // ================= Epilogue: out = x + g * acc =================
    const float g = gamma[0];
    float* op = out + (size_t)b * CIN * HWSZ + hh * WW + ww;
#pragma unroll 4
    for (int c = 0; c < CIN; ++c)
        op[(size_t)c * HWSZ] = xp[(size_t)c * HWSZ] + g * acc[c];
}

extern "C" void kernel_launch(void* const* d_in, const int* in_sizes, int n_in,
                              void* d_out, int out_size, void* d_ws, size_t ws_size,
                              hipStream_t stream) {
    const float* x     = (const float*)d_in[0];
    const float* w1    = (const float*)d_in[1];
    const float* b1    = (const float*)d_in[2];
    const float* w2    = (const float*)d_in[3];
    const float* b2    = (const float*)d_in[4];
    const float* w3    = (const float*)d_in[5];
    const float* b3    = (const float*)d_in[6];
    const float* gamma = (const float*)d_in[7];
    float* out = (float*)d_out;

    dim3 grid(WW / TS, HH / TS, 4);
    fused_local_attn<<<grid, dim3(256), 0, stream>>>(x, w1, b1, w2, b2, w3, b3, gamma, out);
}